// Round 11
// baseline (1173.865 us; speedup 1.0000x reference)
//
#include <hip/hip_runtime.h>
#include <stdint.h>

typedef _Float16 f16;
typedef _Float16 f16x8 __attribute__((ext_vector_type(8)));
typedef short bf16x8 __attribute__((ext_vector_type(8)));
typedef float f32x4 __attribute__((ext_vector_type(4)));

#define H_ 1024
#define NG_ 4096
#define F_ 512
#define B_ 64
#define T_ 128
#define NOP_ 640
#define NO_ 513
#define NBLK_R 128

// Hamilton block structure: W[p-block(in)][q-block(out)] = sign * comp
__constant__ int c_comp[16] = {0,1,2,3, 1,0,3,2, 2,3,0,1, 3,2,1,0};
__constant__ float c_sgnf[16] = {1,1,1,1, -1,1,1,-1, -1,-1,1,1, -1,1,-1,1};

__device__ __forceinline__ float bf2f(unsigned short u){
  union { unsigned int i; float f; } v; v.i = ((unsigned int)u) << 16; return v.f;
}
__device__ __forceinline__ unsigned short f2bf(float f){
  union { float f; unsigned int i; } v; v.f = f;
  return (unsigned short)((v.i + 0x7fffu + ((v.i >> 16) & 1u)) >> 16);
}
__device__ __forceinline__ float ldin(const void* p, int i, int f){
  return f ? ((const float*)p)[i] : bf2f(((const unsigned short*)p)[i]);
}
__device__ __forceinline__ float sigm(float x){ return 1.f / (1.f + __expf(-x)); }
__device__ __forceinline__ float tanh_(float x){
  float ax = fabsf(x);
  float e = __expf(-2.f * ax);
  float t = (1.f - e) / (1.f + e);
  return x < 0.f ? -t : t;
}

// ---- system-coherent (LLC-level) memory ops: bypass L1/L2 ----
__device__ __forceinline__ void load_a8_nw(const f16* p, f16x8* a){
  asm volatile(
    "global_load_dwordx4 %0, %8, off sc0 sc1\n\t"
    "global_load_dwordx4 %1, %8, off offset:64 sc0 sc1\n\t"
    "global_load_dwordx4 %2, %8, off offset:128 sc0 sc1\n\t"
    "global_load_dwordx4 %3, %8, off offset:192 sc0 sc1\n\t"
    "global_load_dwordx4 %4, %8, off offset:256 sc0 sc1\n\t"
    "global_load_dwordx4 %5, %8, off offset:320 sc0 sc1\n\t"
    "global_load_dwordx4 %6, %8, off offset:384 sc0 sc1\n\t"
    "global_load_dwordx4 %7, %8, off offset:448 sc0 sc1"
    : "=&v"(a[0]),"=&v"(a[1]),"=&v"(a[2]),"=&v"(a[3]),
      "=&v"(a[4]),"=&v"(a[5]),"=&v"(a[6]),"=&v"(a[7])
    : "v"(p) : "memory");
}
// cached (L1/L2) batched loads for the x-prefetch — same 64B-stride pattern
__device__ __forceinline__ void load_c8(const unsigned short* p, bf16x8* a){
  asm volatile(
    "global_load_dwordx4 %0, %8, off\n\t"
    "global_load_dwordx4 %1, %8, off offset:64\n\t"
    "global_load_dwordx4 %2, %8, off offset:128\n\t"
    "global_load_dwordx4 %3, %8, off offset:192\n\t"
    "global_load_dwordx4 %4, %8, off offset:256\n\t"
    "global_load_dwordx4 %5, %8, off offset:320\n\t"
    "global_load_dwordx4 %6, %8, off offset:384\n\t"
    "global_load_dwordx4 %7, %8, off offset:448"
    : "=&v"(a[0]),"=&v"(a[1]),"=&v"(a[2]),"=&v"(a[3]),
      "=&v"(a[4]),"=&v"(a[5]),"=&v"(a[6]),"=&v"(a[7])
    : "v"(p) : "memory");
}
__device__ __forceinline__ void store_h_sys(f16* p, f16 v){
  asm volatile("global_store_short %0, %1, off sc0 sc1" :: "v"(p), "v"(v) : "memory");
}
__device__ __forceinline__ void store_flag_sys(int* p, int v){
  asm volatile("global_store_dword %0, %1, off sc0 sc1" :: "v"(p), "v"(v) : "memory");
}
__device__ __forceinline__ void load_flag2_sys(const int* p0, const int* p1, int &a, int &b){
  asm volatile(
    "global_load_dword %0, %2, off sc0 sc1\n\t"
    "global_load_dword %1, %3, off sc0 sc1\n\t"
    "s_waitcnt vmcnt(0)"
    : "=&v"(a), "=&v"(b) : "v"(p0), "v"(p1) : "memory");
}
// issue-only poll round (no wait) — collected later with poll_collect
__device__ __forceinline__ void poll_issue(const int* p0, const int* p1, int &a, int &b){
  asm volatile(
    "global_load_dword %0, %2, off sc0 sc1\n\t"
    "global_load_dword %1, %3, off sc0 sc1"
    : "=&v"(a), "=&v"(b) : "v"(p0), "v"(p1) : "memory");
}
__device__ __forceinline__ void poll_collect(int &a, int &b){
  asm volatile("s_waitcnt vmcnt(0)" : "+v"(a), "+v"(b) :: "memory");
}
__device__ __forceinline__ void drain_vmem(){
  asm volatile("s_waitcnt vmcnt(0)" ::: "memory");
}
#define WAIT_VM(n) do { \
  asm volatile("s_waitcnt vmcnt(" #n ")" ::: "memory"); \
  __builtin_amdgcn_sched_barrier(0); \
} while (0)

// ---- pack: coalesced LDS tile-transposes ----
// sections (blocks): U 1024 | WX 512 | Fco 160 | Xc 1024 | misc 155
#define PK_U_BLKS 1024
#define PK_WX_BLKS 512
#define PK_FCO_BLKS 160
#define PK_XC_BLKS 1024
#define PK_MISC_BLKS 155
#define PK_TOTAL_BLKS (PK_U_BLKS + PK_WX_BLKS + PK_FCO_BLKS + PK_XC_BLKS + PK_MISC_BLKS)

__global__ void pack_kernel(
    const void* __restrict__ x,
    const void* __restrict__ wf, const void* __restrict__ wi,
    const void* __restrict__ wo, const void* __restrict__ wc,
    const void* __restrict__ bfv, const void* __restrict__ biv,
    const void* __restrict__ bov, const void* __restrict__ bcv,
    const void* __restrict__ uf, const void* __restrict__ ui,
    const void* __restrict__ uo, const void* __restrict__ uc,
    const void* __restrict__ fcw, const void* __restrict__ fcb,
    unsigned short* __restrict__ Wx, f16* __restrict__ U, f16* __restrict__ Fco,
    float* __restrict__ bias, float* __restrict__ ob,
    unsigned short* __restrict__ Xc,
    f16* __restrict__ Hz, int* __restrict__ Fz)
{
  __shared__ unsigned short sm[64*68];   // padded 64x64 tile (transpose staging)
  __shared__ int zc, wc2;
  const int tid = threadIdx.x;
  if (tid == 0){ zc = 0; wc2 = 0; }
  __syncthreads();
  {
    const unsigned short* xu = (const unsigned short*)x;
    unsigned short u = xu[2 * tid];
    int e = (u >> 7) & 0xFF;
    bool z = (u & 0x7FFF) == 0;
    bool wild = !z && (e < 67 || e > 150);
    if (z) atomicAdd(&zc, 1);
    if (wild) atomicAdd(&wc2, 1);
  }
  __syncthreads();
  const int fl = (zc >= 128 || wc2 >= 64) ? 1 : 0;

  int b = blockIdx.x;
  if (b < PK_U_BLKS) {
    int g = b >> 8, rem = b & 255;
    int q = rem >> 6, rem2 = rem & 63;
    int p = rem2 >> 4, tt = rem2 & 15;
    int alt = (tt >> 2) * 64, bet = (tt & 3) * 64;
    const void* u = (g==0) ? uf : (g==1) ? ui : (g==2) ? uo : uc;
    int pq = p*4 + q;
    int base_in = c_comp[pq]*65536 + alt*256 + bet;
    float sgn = c_sgnf[pq];
    f16* smf = (f16*)sm;
    #pragma unroll
    for (int j = 0; j < 16; j++) {
      int idx = tid + j*256;
      int al = idx >> 6, be = idx & 63;
      smf[al*68 + be] = (f16)(sgn * ldin(u, base_in + al*256 + be, fl));
    }
    __syncthreads();
    size_t obase = (size_t)(g*1024 + q*256 + bet) * 1024 + p*256 + alt;
    #pragma unroll
    for (int j = 0; j < 16; j++) {
      int idx = tid + j*256;
      int be = idx >> 6, al = idx & 63;
      U[obase + (size_t)be*1024 + al] = smf[al*68 + be];
    }
    return;
  }
  b -= PK_U_BLKS;
  if (b < PK_WX_BLKS) {
    int g = b >> 7, rem = b & 127;
    int q = rem >> 5, rem2 = rem & 31;
    int p = rem2 >> 3, tt = rem2 & 7;
    int alt = (tt >> 2) * 64, bet = (tt & 3) * 64;
    const void* w = (g==0) ? wf : (g==1) ? wi : (g==2) ? wo : wc;
    int pq = p*4 + q;
    int base_in = c_comp[pq]*32768 + alt*256 + bet;
    float sgn = c_sgnf[pq];
    #pragma unroll
    for (int j = 0; j < 16; j++) {
      int idx = tid + j*256;
      int al = idx >> 6, be = idx & 63;
      sm[al*68 + be] = f2bf(sgn * ldin(w, base_in + al*256 + be, fl));
    }
    __syncthreads();
    size_t obase = (size_t)(g*1024 + q*256 + bet) * 512 + p*128 + alt;
    #pragma unroll
    for (int j = 0; j < 16; j++) {
      int idx = tid + j*256;
      int be = idx >> 6, al = idx & 63;
      Wx[obase + (size_t)be*512 + al] = sm[al*68 + be];
    }
    return;
  }
  b -= PK_WX_BLKS;
  if (b < PK_FCO_BLKS) {
    int kt = b / 10, nt2 = b % 10;
    int k0 = kt*64, n0 = nt2*64;
    f16* smf = (f16*)sm;
    #pragma unroll
    for (int j = 0; j < 16; j++) {
      int idx = tid + j*256;
      int kk = idx >> 6, nn = idx & 63;
      int n = n0 + nn;
      smf[kk*68 + nn] = (n < NO_) ? (f16)ldin(fcw, (k0+kk)*NO_ + n, fl) : (f16)0.f;
    }
    __syncthreads();
    #pragma unroll
    for (int j = 0; j < 16; j++) {
      int idx = tid + j*256;
      int nn = idx >> 6, kk = idx & 63;
      Fco[(size_t)(n0+nn)*1024 + k0 + kk] = smf[kk*68 + nn];
    }
    return;
  }
  b -= PK_FCO_BLKS;
  if (b < PK_XC_BLKS) {
    unsigned int* Xo = (unsigned int*)Xc;
    if (fl) {
      const float* xf = (const float*)x;
      #pragma unroll
      for (int j = 0; j < 8; j++) {
        int o = b*2048 + tid + j*256;
        unsigned int lo16 = f2bf(xf[2*o]);
        unsigned int hi16 = f2bf(xf[2*o+1]);
        Xo[o] = lo16 | (hi16 << 16);
      }
    } else {
      const unsigned int* xi = (const unsigned int*)x;
      #pragma unroll
      for (int j = 0; j < 8; j++) {
        int o = b*2048 + tid + j*256;
        Xo[o] = xi[o];
      }
    }
    return;
  }
  b -= PK_XC_BLKS;
  {
    int i = b*256 + tid;
    if (i < 4096) {
      int g = i >> 10;
      const void* bb = (g==0) ? bfv : (g==1) ? biv : (g==2) ? bov : bcv;
      bias[i] = ldin(bb, i & 1023, fl);
      return;
    }
    i -= 4096;
    if (i < 640) { ob[i] = (i < NO_) ? ldin(fcb, i, fl) : 0.f; return; }
    i -= 640;
    if (i < 32768) { ((unsigned int*)Hz)[i] = 0u; return; }
    i -= 32768;
    if (i < 2048) { Fz[i] = 0; }
  }
}

// Persistent cooperative recurrence, ALL 128 steps in one launch.
// 128 blocks x 256 thr (4 waves). Block owns cols jb..jb+8 for ALL 4 gates.
// Step tail: split x-MFMA shadow (half A hides store-ack, half B hides flag
// propagation) + pipelined poll (first round issued before shadow half B).
// Launch structure IDENTICAL to round-9 (6 args, separate gemm_out).
__global__ __launch_bounds__(256) void recur_all(
    const unsigned short* __restrict__ Xc,
    const unsigned short* __restrict__ Wxp,
    const f16* __restrict__ U,
    const float* __restrict__ bias,
    f16* __restrict__ Hall,
    int* __restrict__ flags)
{
  __shared__ f16 Usm[32768];             // 64 KB: frag f = ki*2+nt (64), 512 f16
  __shared__ unsigned short Wxsm[16384]; // 32 KB: frag f = u*2+p (32), 512 bf16
  const int blk = blockIdx.x;
  const int jb = blk * 8;
  const int tid = threadIdx.x;
  const int lane = tid & 63, w = tid >> 6;
  const int lo = lane & 15, quad = lane >> 4;
  const int m0 = w * 16;

  #pragma unroll
  for (int j = 0; j < 16; j++) {
    int u = tid + j*256;
    int lp = u & 63, f = u >> 6;
    int ki = f >> 1, nt = f & 1;
    int n = nt*16 + (lp & 15), qd = lp >> 4;
    int row = (n >> 3)*H_ + jb + (n & 7);
    *(f16x8*)(Usm + f*512 + lp*8) =
        *(const f16x8*)(U + (size_t)row*H_ + ki*32 + qd*8);
  }
  #pragma unroll
  for (int j = 0; j < 8; j++) {
    int u = tid + j*256;
    int lp = u & 63, f = u >> 6;      // f = ku*2 + p
    int ku = f >> 1, p = f & 1;
    int col = (p*2 + ((lp & 15) >> 3))*1024 + jb + (lp & 7);
    *(f16x8*)((f16*)Wxsm + f*512 + lp*8) =
        *(const f16x8*)((const f16*)Wxp + (size_t)col*F_ + ku*32 + (lp >> 4)*8);
  }
  const int cc = lane & 7, hi = (lane >> 3) & 1;
  const int colg = jb + cc;
  const int b0r = m0 + quad*4 + hi*2;
  float creg[2] = {0.f, 0.f};
  const float bf0 = bias[colg];
  const float bf1 = bias[1024 + colg];
  const float bf2 = bias[2048 + colg];
  const float bf3 = bias[3072 + colg];
  __syncthreads();

  f32x4 xp0 = {0.f,0.f,0.f,0.f}, xp1 = {0.f,0.f,0.f,0.f};
  bf16x8 xa0[8], xa1[8];
  {
    const unsigned short* xr = Xc + (size_t)(m0 + lo)*F_ + quad*8;
    load_c8(xr, xa0);
    load_c8(xr + 256, xa1);
    drain_vmem();
    __builtin_amdgcn_sched_barrier(0);
    #pragma unroll
    for (int u = 0; u < 8; u++) {
      xp0 = __builtin_amdgcn_mfma_f32_16x16x32_bf16(xa0[u], *(const bf16x8*)((f16*)Wxsm + (u*2+0)*512 + lane*8), xp0, 0, 0, 0);
      xp1 = __builtin_amdgcn_mfma_f32_16x16x32_bf16(xa0[u], *(const bf16x8*)((f16*)Wxsm + (u*2+1)*512 + lane*8), xp1, 0, 0, 0);
    }
    #pragma unroll
    for (int u = 0; u < 8; u++) {
      xp0 = __builtin_amdgcn_mfma_f32_16x16x32_bf16(xa1[u], *(const bf16x8*)((f16*)Wxsm + ((8+u)*2+0)*512 + lane*8), xp0, 0, 0, 0);
      xp1 = __builtin_amdgcn_mfma_f32_16x16x32_bf16(xa1[u], *(const bf16x8*)((f16*)Wxsm + ((8+u)*2+1)*512 + lane*8), xp1, 0, 0, 0);
    }
  }

  for (int t = 0; t < T_; t++) {
    f32x4 acc0 = xp0, acc1 = xp1;
    const f16* Ap = Hall + (size_t)t*B_*H_ + (size_t)(m0 + lo)*H_ + quad*8;
    f16x8 a0[8], a1[8], a2[8], a3[8];
    drain_vmem();
    load_a8_nw(Ap,       a0);
    load_a8_nw(Ap + 256, a1);
    load_a8_nw(Ap + 512, a2);
    load_a8_nw(Ap + 768, a3);
    {
      const int tn = (t + 1 < T_) ? t + 1 : 0;
      const unsigned short* xr = Xc + (size_t)tn*B_*F_ + (size_t)(m0 + lo)*F_ + quad*8;
      load_c8(xr, xa0);
      load_c8(xr + 256, xa1);
    }
    WAIT_VM(40);
    #pragma unroll
    for (int u = 0; u < 8; u++) {
      f16x8 bb0 = *(const f16x8*)(Usm + ((u)*2+0)*512 + lane*8);
      f16x8 bb1 = *(const f16x8*)(Usm + ((u)*2+1)*512 + lane*8);
      acc0 = __builtin_amdgcn_mfma_f32_16x16x32_f16(a0[u], bb0, acc0, 0, 0, 0);
      acc1 = __builtin_amdgcn_mfma_f32_16x16x32_f16(a0[u], bb1, acc1, 0, 0, 0);
    }
    WAIT_VM(32);
    #pragma unroll
    for (int u = 0; u < 8; u++) {
      f16x8 bb0 = *(const f16x8*)(Usm + ((8+u)*2+0)*512 + lane*8);
      f16x8 bb1 = *(const f16x8*)(Usm + ((8+u)*2+1)*512 + lane*8);
      acc0 = __builtin_amdgcn_mfma_f32_16x16x32_f16(a1[u], bb0, acc0, 0, 0, 0);
      acc1 = __builtin_amdgcn_mfma_f32_16x16x32_f16(a1[u], bb1, acc1, 0, 0, 0);
    }
    WAIT_VM(24);
    #pragma unroll
    for (int u = 0; u < 8; u++) {
      f16x8 bb0 = *(const f16x8*)(Usm + ((16+u)*2+0)*512 + lane*8);
      f16x8 bb1 = *(const f16x8*)(Usm + ((16+u)*2+1)*512 + lane*8);
      acc0 = __builtin_amdgcn_mfma_f32_16x16x32_f16(a2[u], bb0, acc0, 0, 0, 0);
      acc1 = __builtin_amdgcn_mfma_f32_16x16x32_f16(a2[u], bb1, acc1, 0, 0, 0);
    }
    WAIT_VM(16);
    #pragma unroll
    for (int u = 0; u < 8; u++) {
      f16x8 bb0 = *(const f16x8*)(Usm + ((24+u)*2+0)*512 + lane*8);
      f16x8 bb1 = *(const f16x8*)(Usm + ((24+u)*2+1)*512 + lane*8);
      acc0 = __builtin_amdgcn_mfma_f32_16x16x32_f16(a3[u], bb0, acc0, 0, 0, 0);
      acc1 = __builtin_amdgcn_mfma_f32_16x16x32_f16(a3[u], bb1, acc1, 0, 0, 0);
    }
    WAIT_VM(0);
    f16* Hn = Hall + (size_t)(t+1)*B_*H_;
    #pragma unroll
    for (int e = 0; e < 2; e++) {
      int src = quad*16 + cc;
      float f_lo = __shfl(acc0[e],   src);
      float f_hi = __shfl(acc0[2+e], src);
      float i_lo = __shfl(acc0[e],   src + 8);
      float i_hi = __shfl(acc0[2+e], src + 8);
      float o_lo = __shfl(acc1[e],   src);
      float o_hi = __shfl(acc1[2+e], src);
      float a_lo = __shfl(acc1[e],   src + 8);
      float a_hi = __shfl(acc1[2+e], src + 8);
      float pf = (hi ? f_hi : f_lo) + bf0;
      float pi = (hi ? i_hi : i_lo) + bf1;
      float po = (hi ? o_hi : o_lo) + bf2;
      float pa = (hi ? a_hi : a_lo) + bf3;
      float vf = sigm(pf), vi = sigm(pi), vo = sigm(po);
      creg[e] = vi * tanh_(pa) + vf * creg[e];
      float hn = vo * tanh_(creg[e]);
      store_h_sys(Hn + (size_t)(b0r + e)*H_ + colg, (f16)hn);
    }
    if (t + 1 < T_) {
      // shadow half A: hides the h-store ack (reg/LDS only)
      xp0 = (f32x4){0.f,0.f,0.f,0.f};
      xp1 = (f32x4){0.f,0.f,0.f,0.f};
      #pragma unroll
      for (int u = 0; u < 8; u++) {
        xp0 = __builtin_amdgcn_mfma_f32_16x16x32_bf16(xa0[u], *(const bf16x8*)((f16*)Wxsm + (u*2+0)*512 + lane*8), xp0, 0, 0, 0);
        xp1 = __builtin_amdgcn_mfma_f32_16x16x32_bf16(xa0[u], *(const bf16x8*)((f16*)Wxsm + (u*2+1)*512 + lane*8), xp1, 0, 0, 0);
      }
      drain_vmem();
      __syncthreads();
      const int target = t + 1;
      if (tid == 0) store_flag_sys(flags + blk*16, target);
      int pf0 = 0, pf1 = 0;
      const int* fp0 = flags + (2*lane)*16;
      const int* fp1 = flags + (2*lane+1)*16;
      if (w == 0) poll_issue(fp0, fp1, pf0, pf1);
      // shadow half B: hides flag propagation + first poll round latency
      #pragma unroll
      for (int u = 0; u < 8; u++) {
        xp0 = __builtin_amdgcn_mfma_f32_16x16x32_bf16(xa1[u], *(const bf16x8*)((f16*)Wxsm + ((8+u)*2+0)*512 + lane*8), xp0, 0, 0, 0);
        xp1 = __builtin_amdgcn_mfma_f32_16x16x32_bf16(xa1[u], *(const bf16x8*)((f16*)Wxsm + ((8+u)*2+1)*512 + lane*8), xp1, 0, 0, 0);
      }
      __builtin_amdgcn_sched_barrier(0);
      if (w == 0) {
        poll_collect(pf0, pf1);
        while (!__all(pf0 >= target && pf1 >= target))
          load_flag2_sys(fp0, fp1, pf0, pf1);
      }
      __syncthreads();
    } else {
      drain_vmem();             // final h state visible to gemm_out dispatch
    }
  }
}

// out = Hall[1..128] @ Fco^T-layout + ob : M=8192, N=640(pad), K=1024, fp32 out
__global__ __launch_bounds__(256) void gemm_out(
    const f16* __restrict__ A,
    const f16* __restrict__ Bt,
    const float* __restrict__ ob,
    float* __restrict__ out)
{
  const int lane = threadIdx.x & 63, w = threadIdx.x >> 6;
  const int lo = lane & 15, quad = lane >> 4;
  const int m0 = blockIdx.x * 128 + (w >> 1) * 64;
  const int n0 = blockIdx.y * 128 + (w & 1) * 64;
  f32x4 acc[4][4] = {};
  #pragma unroll 2
  for (int k0 = 0; k0 < H_; k0 += 32) {
    f16x8 a[4], b[4];
    #pragma unroll
    for (int mt = 0; mt < 4; mt++)
      a[mt] = *(const f16x8*)(A + (size_t)(m0 + 16*mt + lo) * H_ + k0 + quad*8);
    #pragma unroll
    for (int nt = 0; nt < 4; nt++)
      b[nt] = *(const f16x8*)(Bt + (size_t)(n0 + 16*nt + lo) * H_ + k0 + quad*8);
    #pragma unroll
    for (int mt = 0; mt < 4; mt++)
      #pragma unroll
      for (int nt = 0; nt < 4; nt++)
        acc[mt][nt] = __builtin_amdgcn_mfma_f32_16x16x32_f16(a[mt], b[nt], acc[mt][nt], 0, 0, 0);
  }
  #pragma unroll
  for (int mt = 0; mt < 4; mt++)
    #pragma unroll
    for (int nt = 0; nt < 4; nt++)
      #pragma unroll
      for (int r = 0; r < 4; r++) {
        int row = m0 + 16*mt + quad*4 + r;
        int col = n0 + 16*nt + lo;
        if (col < NO_)
          out[(size_t)row * NO_ + col] = acc[mt][nt][r] + ob[col];
      }
}

extern "C" void kernel_launch(void* const* d_in, const int* in_sizes, int n_in,
                              void* d_out, int out_size, void* d_ws, size_t ws_size,
                              hipStream_t stream)
{
  const void* x   = d_in[0];
  const void* wfw = d_in[1];  const void* wfb = d_in[2];
  const void* wiw = d_in[3];  const void* wib = d_in[4];
  const void* wow = d_in[5];  const void* wob = d_in[6];
  const void* wcw = d_in[7];  const void* wcb = d_in[8];
  const void* ufw = d_in[9];  const void* uiw = d_in[10];
  const void* uow = d_in[11]; const void* ucw = d_in[12];
  const void* fcw = d_in[13]; const void* fcb = d_in[14];

  char* ws = (char*)d_ws;
  unsigned short* Wx = (unsigned short*)(ws + 0);        //  4,194,304 B
  f16*   U    = (f16*)  (ws + 4194304);                  //  8,388,608 B
  f16*   Fco  = (f16*)  (ws + 12582912);                 //  1,310,720 B
  unsigned short* Xc = (unsigned short*)(ws + 13893632); //  8,388,608 B
  f16*   Hall = (f16*)  (ws + 22282240);                 // 16,908,288 B (129 states)
  float* bias = (float*)(ws + 39190528);                 //     16,384 B
  float* ob   = (float*)(ws + 39206912);                 //      2,560 B
  int*   flags= (int*)  (ws + 39209472);                 //      8,192 B (128 x 64B)
  if (ws_size < 39217664u) return;

  pack_kernel<<<PK_TOTAL_BLKS, 256, 0, stream>>>(
      x, wfw, wiw, wow, wcw, wfb, wib, wob, wcb, ufw, uiw, uow, ucw, fcw, fcb,
      Wx, U, Fco, bias, ob, Xc, Hall, flags);

  {
    const unsigned short* Xcp = Xc;
    const unsigned short* Wxp = Wx;
    const f16* Up = U;
    const float* bp = bias;
    f16* Hp = Hall;
    int* flp = flags;
    void* args[] = {&Xcp, &Wxp, &Up, &bp, &Hp, &flp};
    hipLaunchCooperativeKernel((const void*)recur_all, dim3(NBLK_R), dim3(256),
                               args, 0, stream);
  }

  gemm_out<<<dim3(64, 5), 256, 0, stream>>>(Hall + (size_t)B_*H_, Fco, ob, (float*)d_out);
}

// Round 12
// 1173.785 us; speedup vs baseline: 1.0001x; 1.0001x over previous
//
#include <hip/hip_runtime.h>
#include <stdint.h>

typedef _Float16 f16;
typedef _Float16 f16x8 __attribute__((ext_vector_type(8)));
typedef short bf16x8 __attribute__((ext_vector_type(8)));
typedef float f32x4 __attribute__((ext_vector_type(4)));

#define H_ 1024
#define NG_ 4096
#define F_ 512
#define B_ 64
#define T_ 128
#define NOP_ 640
#define NO_ 513
#define NBLK_R 128

// Hamilton block structure: W[p-block(in)][q-block(out)] = sign * comp
__constant__ int c_comp[16] = {0,1,2,3, 1,0,3,2, 2,3,0,1, 3,2,1,0};
__constant__ float c_sgnf[16] = {1,1,1,1, -1,1,1,-1, -1,-1,1,1, -1,1,-1,1};

__device__ __forceinline__ float bf2f(unsigned short u){
  union { unsigned int i; float f; } v; v.i = ((unsigned int)u) << 16; return v.f;
}
__device__ __forceinline__ unsigned short f2bf(float f){
  union { float f; unsigned int i; } v; v.f = f;
  return (unsigned short)((v.i + 0x7fffu + ((v.i >> 16) & 1u)) >> 16);
}
__device__ __forceinline__ float ldin(const void* p, int i, int f){
  return f ? ((const float*)p)[i] : bf2f(((const unsigned short*)p)[i]);
}
__device__ __forceinline__ float sigm(float x){ return 1.f / (1.f + __expf(-x)); }
__device__ __forceinline__ float tanh_(float x){
  float ax = fabsf(x);
  float e = __expf(-2.f * ax);
  float t = (1.f - e) / (1.f + e);
  return x < 0.f ? -t : t;
}

// ---- system-coherent (LLC-level) memory ops: bypass L1/L2 ----
__device__ __forceinline__ void load_a8_nw(const f16* p, f16x8* a){
  asm volatile(
    "global_load_dwordx4 %0, %8, off sc0 sc1\n\t"
    "global_load_dwordx4 %1, %8, off offset:64 sc0 sc1\n\t"
    "global_load_dwordx4 %2, %8, off offset:128 sc0 sc1\n\t"
    "global_load_dwordx4 %3, %8, off offset:192 sc0 sc1\n\t"
    "global_load_dwordx4 %4, %8, off offset:256 sc0 sc1\n\t"
    "global_load_dwordx4 %5, %8, off offset:320 sc0 sc1\n\t"
    "global_load_dwordx4 %6, %8, off offset:384 sc0 sc1\n\t"
    "global_load_dwordx4 %7, %8, off offset:448 sc0 sc1"
    : "=&v"(a[0]),"=&v"(a[1]),"=&v"(a[2]),"=&v"(a[3]),
      "=&v"(a[4]),"=&v"(a[5]),"=&v"(a[6]),"=&v"(a[7])
    : "v"(p) : "memory");
}
// cached (L1/L2) batched loads for the x-prefetch — same 64B-stride pattern
__device__ __forceinline__ void load_c8(const unsigned short* p, bf16x8* a){
  asm volatile(
    "global_load_dwordx4 %0, %8, off\n\t"
    "global_load_dwordx4 %1, %8, off offset:64\n\t"
    "global_load_dwordx4 %2, %8, off offset:128\n\t"
    "global_load_dwordx4 %3, %8, off offset:192\n\t"
    "global_load_dwordx4 %4, %8, off offset:256\n\t"
    "global_load_dwordx4 %5, %8, off offset:320\n\t"
    "global_load_dwordx4 %6, %8, off offset:384\n\t"
    "global_load_dwordx4 %7, %8, off offset:448"
    : "=&v"(a[0]),"=&v"(a[1]),"=&v"(a[2]),"=&v"(a[3]),
      "=&v"(a[4]),"=&v"(a[5]),"=&v"(a[6]),"=&v"(a[7])
    : "v"(p) : "memory");
}
__device__ __forceinline__ void store_h_sys(f16* p, f16 v){
  asm volatile("global_store_short %0, %1, off sc0 sc1" :: "v"(p), "v"(v) : "memory");
}
__device__ __forceinline__ void store_flag_sys(int* p, int v){
  asm volatile("global_store_dword %0, %1, off sc0 sc1" :: "v"(p), "v"(v) : "memory");
}
__device__ __forceinline__ void load_flag2_sys(const int* p0, const int* p1, int &a, int &b){
  asm volatile(
    "global_load_dword %0, %2, off sc0 sc1\n\t"
    "global_load_dword %1, %3, off sc0 sc1\n\t"
    "s_waitcnt vmcnt(0)"
    : "=&v"(a), "=&v"(b) : "v"(p0), "v"(p1) : "memory");
}
// issue-only poll round (no wait) — collected later with poll_collect
__device__ __forceinline__ void poll_issue(const int* p0, const int* p1, int &a, int &b){
  asm volatile(
    "global_load_dword %0, %2, off sc0 sc1\n\t"
    "global_load_dword %1, %3, off sc0 sc1"
    : "=&v"(a), "=&v"(b) : "v"(p0), "v"(p1) : "memory");
}
__device__ __forceinline__ void poll_collect(int &a, int &b){
  asm volatile("s_waitcnt vmcnt(0)" : "+v"(a), "+v"(b) :: "memory");
}
__device__ __forceinline__ void drain_vmem(){
  asm volatile("s_waitcnt vmcnt(0)" ::: "memory");
}
#define WAIT_VM(n) do { \
  asm volatile("s_waitcnt vmcnt(" #n ")" ::: "memory"); \
  __builtin_amdgcn_sched_barrier(0); \
} while (0)

// ---- pack: coalesced LDS tile-transposes ----
// sections (blocks): U 1024 | WX 512 | Fco 160 | Xc 1024 | misc 155
#define PK_U_BLKS 1024
#define PK_WX_BLKS 512
#define PK_FCO_BLKS 160
#define PK_XC_BLKS 1024
#define PK_MISC_BLKS 155
#define PK_TOTAL_BLKS (PK_U_BLKS + PK_WX_BLKS + PK_FCO_BLKS + PK_XC_BLKS + PK_MISC_BLKS)

__global__ void pack_kernel(
    const void* __restrict__ x,
    const void* __restrict__ wf, const void* __restrict__ wi,
    const void* __restrict__ wo, const void* __restrict__ wc,
    const void* __restrict__ bfv, const void* __restrict__ biv,
    const void* __restrict__ bov, const void* __restrict__ bcv,
    const void* __restrict__ uf, const void* __restrict__ ui,
    const void* __restrict__ uo, const void* __restrict__ uc,
    const void* __restrict__ fcw, const void* __restrict__ fcb,
    unsigned short* __restrict__ Wx, f16* __restrict__ U, f16* __restrict__ Fco,
    float* __restrict__ bias, float* __restrict__ ob,
    unsigned short* __restrict__ Xc,
    f16* __restrict__ Hz, int* __restrict__ Fz)
{
  __shared__ unsigned short sm[64*68];   // padded 64x64 tile (transpose staging)
  __shared__ int zc, wc2;
  const int tid = threadIdx.x;
  if (tid == 0){ zc = 0; wc2 = 0; }
  __syncthreads();
  {
    const unsigned short* xu = (const unsigned short*)x;
    unsigned short u = xu[2 * tid];
    int e = (u >> 7) & 0xFF;
    bool z = (u & 0x7FFF) == 0;
    bool wild = !z && (e < 67 || e > 150);
    if (z) atomicAdd(&zc, 1);
    if (wild) atomicAdd(&wc2, 1);
  }
  __syncthreads();
  const int fl = (zc >= 128 || wc2 >= 64) ? 1 : 0;

  int b = blockIdx.x;
  if (b < PK_U_BLKS) {
    int g = b >> 8, rem = b & 255;
    int q = rem >> 6, rem2 = rem & 63;
    int p = rem2 >> 4, tt = rem2 & 15;
    int alt = (tt >> 2) * 64, bet = (tt & 3) * 64;
    const void* u = (g==0) ? uf : (g==1) ? ui : (g==2) ? uo : uc;
    int pq = p*4 + q;
    int base_in = c_comp[pq]*65536 + alt*256 + bet;
    float sgn = c_sgnf[pq];
    f16* smf = (f16*)sm;
    #pragma unroll
    for (int j = 0; j < 16; j++) {
      int idx = tid + j*256;
      int al = idx >> 6, be = idx & 63;
      smf[al*68 + be] = (f16)(sgn * ldin(u, base_in + al*256 + be, fl));
    }
    __syncthreads();
    size_t obase = (size_t)(g*1024 + q*256 + bet) * 1024 + p*256 + alt;
    #pragma unroll
    for (int j = 0; j < 16; j++) {
      int idx = tid + j*256;
      int be = idx >> 6, al = idx & 63;
      U[obase + (size_t)be*1024 + al] = smf[al*68 + be];
    }
    return;
  }
  b -= PK_U_BLKS;
  if (b < PK_WX_BLKS) {
    int g = b >> 7, rem = b & 127;
    int q = rem >> 5, rem2 = rem & 31;
    int p = rem2 >> 3, tt = rem2 & 7;
    int alt = (tt >> 2) * 64, bet = (tt & 3) * 64;
    const void* w = (g==0) ? wf : (g==1) ? wi : (g==2) ? wo : wc;
    int pq = p*4 + q;
    int base_in = c_comp[pq]*32768 + alt*256 + bet;
    float sgn = c_sgnf[pq];
    #pragma unroll
    for (int j = 0; j < 16; j++) {
      int idx = tid + j*256;
      int al = idx >> 6, be = idx & 63;
      sm[al*68 + be] = f2bf(sgn * ldin(w, base_in + al*256 + be, fl));
    }
    __syncthreads();
    size_t obase = (size_t)(g*1024 + q*256 + bet) * 512 + p*128 + alt;
    #pragma unroll
    for (int j = 0; j < 16; j++) {
      int idx = tid + j*256;
      int be = idx >> 6, al = idx & 63;
      Wx[obase + (size_t)be*512 + al] = sm[al*68 + be];
    }
    return;
  }
  b -= PK_WX_BLKS;
  if (b < PK_FCO_BLKS) {
    int kt = b / 10, nt2 = b % 10;
    int k0 = kt*64, n0 = nt2*64;
    f16* smf = (f16*)sm;
    #pragma unroll
    for (int j = 0; j < 16; j++) {
      int idx = tid + j*256;
      int kk = idx >> 6, nn = idx & 63;
      int n = n0 + nn;
      smf[kk*68 + nn] = (n < NO_) ? (f16)ldin(fcw, (k0+kk)*NO_ + n, fl) : (f16)0.f;
    }
    __syncthreads();
    #pragma unroll
    for (int j = 0; j < 16; j++) {
      int idx = tid + j*256;
      int nn = idx >> 6, kk = idx & 63;
      Fco[(size_t)(n0+nn)*1024 + k0 + kk] = smf[kk*68 + nn];
    }
    return;
  }
  b -= PK_FCO_BLKS;
  if (b < PK_XC_BLKS) {
    unsigned int* Xo = (unsigned int*)Xc;
    if (fl) {
      const float* xf = (const float*)x;
      #pragma unroll
      for (int j = 0; j < 8; j++) {
        int o = b*2048 + tid + j*256;
        unsigned int lo16 = f2bf(xf[2*o]);
        unsigned int hi16 = f2bf(xf[2*o+1]);
        Xo[o] = lo16 | (hi16 << 16);
      }
    } else {
      const unsigned int* xi = (const unsigned int*)x;
      #pragma unroll
      for (int j = 0; j < 8; j++) {
        int o = b*2048 + tid + j*256;
        Xo[o] = xi[o];
      }
    }
    return;
  }
  b -= PK_XC_BLKS;
  {
    int i = b*256 + tid;
    if (i < 4096) {
      int g = i >> 10;
      const void* bb = (g==0) ? bfv : (g==1) ? biv : (g==2) ? bov : bcv;
      bias[i] = ldin(bb, i & 1023, fl);
      return;
    }
    i -= 4096;
    if (i < 640) { ob[i] = (i < NO_) ? ldin(fcb, i, fl) : 0.f; return; }
    i -= 640;
    if (i < 32768) { ((unsigned int*)Hz)[i] = 0u; return; }
    i -= 32768;
    if (i < 2048) { Fz[i] = 0; }
  }
}

// Persistent cooperative recurrence, ALL 128 steps in one launch.
// 128 blocks x 256 thr (4 waves). Block owns cols jb..jb+8 for ALL 4 gates.
// Step tail (round-9 order + pipelined poll): drain -> syncthreads ->
// tid0 flag post -> poll round 1 ISSUED -> 32 x-MFMAs (shadow) ->
// poll collect + retry -> syncthreads.
__global__ __launch_bounds__(256) void recur_all(
    const unsigned short* __restrict__ Xc,
    const unsigned short* __restrict__ Wxp,
    const f16* __restrict__ U,
    const float* __restrict__ bias,
    f16* __restrict__ Hall,
    int* __restrict__ flags)
{
  __shared__ f16 Usm[32768];             // 64 KB: frag f = ki*2+nt (64), 512 f16
  __shared__ unsigned short Wxsm[16384]; // 32 KB: frag f = u*2+p (32), 512 bf16
  const int blk = blockIdx.x;
  const int jb = blk * 8;
  const int tid = threadIdx.x;
  const int lane = tid & 63, w = tid >> 6;
  const int lo = lane & 15, quad = lane >> 4;
  const int m0 = w * 16;

  #pragma unroll
  for (int j = 0; j < 16; j++) {
    int u = tid + j*256;
    int lp = u & 63, f = u >> 6;
    int ki = f >> 1, nt = f & 1;
    int n = nt*16 + (lp & 15), qd = lp >> 4;
    int row = (n >> 3)*H_ + jb + (n & 7);
    *(f16x8*)(Usm + f*512 + lp*8) =
        *(const f16x8*)(U + (size_t)row*H_ + ki*32 + qd*8);
  }
  #pragma unroll
  for (int j = 0; j < 8; j++) {
    int u = tid + j*256;
    int lp = u & 63, f = u >> 6;      // f = ku*2 + p
    int ku = f >> 1, p = f & 1;
    int col = (p*2 + ((lp & 15) >> 3))*1024 + jb + (lp & 7);
    *(f16x8*)((f16*)Wxsm + f*512 + lp*8) =
        *(const f16x8*)((const f16*)Wxp + (size_t)col*F_ + ku*32 + (lp >> 4)*8);
  }
  const int cc = lane & 7, hi = (lane >> 3) & 1;
  const int colg = jb + cc;
  const int b0r = m0 + quad*4 + hi*2;
  float creg[2] = {0.f, 0.f};
  const float bf0 = bias[colg];
  const float bf1 = bias[1024 + colg];
  const float bf2 = bias[2048 + colg];
  const float bf3 = bias[3072 + colg];
  __syncthreads();

  f32x4 xp0 = {0.f,0.f,0.f,0.f}, xp1 = {0.f,0.f,0.f,0.f};
  bf16x8 xa0[8], xa1[8];
  {
    const unsigned short* xr = Xc + (size_t)(m0 + lo)*F_ + quad*8;
    load_c8(xr, xa0);
    load_c8(xr + 256, xa1);
    drain_vmem();
    __builtin_amdgcn_sched_barrier(0);
    #pragma unroll
    for (int u = 0; u < 8; u++) {
      xp0 = __builtin_amdgcn_mfma_f32_16x16x32_bf16(xa0[u], *(const bf16x8*)((f16*)Wxsm + (u*2+0)*512 + lane*8), xp0, 0, 0, 0);
      xp1 = __builtin_amdgcn_mfma_f32_16x16x32_bf16(xa0[u], *(const bf16x8*)((f16*)Wxsm + (u*2+1)*512 + lane*8), xp1, 0, 0, 0);
    }
    #pragma unroll
    for (int u = 0; u < 8; u++) {
      xp0 = __builtin_amdgcn_mfma_f32_16x16x32_bf16(xa1[u], *(const bf16x8*)((f16*)Wxsm + ((8+u)*2+0)*512 + lane*8), xp0, 0, 0, 0);
      xp1 = __builtin_amdgcn_mfma_f32_16x16x32_bf16(xa1[u], *(const bf16x8*)((f16*)Wxsm + ((8+u)*2+1)*512 + lane*8), xp1, 0, 0, 0);
    }
  }

  for (int t = 0; t < T_; t++) {
    f32x4 acc0 = xp0, acc1 = xp1;
    const f16* Ap = Hall + (size_t)t*B_*H_ + (size_t)(m0 + lo)*H_ + quad*8;
    f16x8 a0[8], a1[8], a2[8], a3[8];
    drain_vmem();
    load_a8_nw(Ap,       a0);
    load_a8_nw(Ap + 256, a1);
    load_a8_nw(Ap + 512, a2);
    load_a8_nw(Ap + 768, a3);
    {
      const int tn = (t + 1 < T_) ? t + 1 : 0;
      const unsigned short* xr = Xc + (size_t)tn*B_*F_ + (size_t)(m0 + lo)*F_ + quad*8;
      load_c8(xr, xa0);
      load_c8(xr + 256, xa1);
    }
    WAIT_VM(40);
    #pragma unroll
    for (int u = 0; u < 8; u++) {
      f16x8 bb0 = *(const f16x8*)(Usm + ((u)*2+0)*512 + lane*8);
      f16x8 bb1 = *(const f16x8*)(Usm + ((u)*2+1)*512 + lane*8);
      acc0 = __builtin_amdgcn_mfma_f32_16x16x32_f16(a0[u], bb0, acc0, 0, 0, 0);
      acc1 = __builtin_amdgcn_mfma_f32_16x16x32_f16(a0[u], bb1, acc1, 0, 0, 0);
    }
    WAIT_VM(32);
    #pragma unroll
    for (int u = 0; u < 8; u++) {
      f16x8 bb0 = *(const f16x8*)(Usm + ((8+u)*2+0)*512 + lane*8);
      f16x8 bb1 = *(const f16x8*)(Usm + ((8+u)*2+1)*512 + lane*8);
      acc0 = __builtin_amdgcn_mfma_f32_16x16x32_f16(a1[u], bb0, acc0, 0, 0, 0);
      acc1 = __builtin_amdgcn_mfma_f32_16x16x32_f16(a1[u], bb1, acc1, 0, 0, 0);
    }
    WAIT_VM(24);
    #pragma unroll
    for (int u = 0; u < 8; u++) {
      f16x8 bb0 = *(const f16x8*)(Usm + ((16+u)*2+0)*512 + lane*8);
      f16x8 bb1 = *(const f16x8*)(Usm + ((16+u)*2+1)*512 + lane*8);
      acc0 = __builtin_amdgcn_mfma_f32_16x16x32_f16(a2[u], bb0, acc0, 0, 0, 0);
      acc1 = __builtin_amdgcn_mfma_f32_16x16x32_f16(a2[u], bb1, acc1, 0, 0, 0);
    }
    WAIT_VM(16);
    #pragma unroll
    for (int u = 0; u < 8; u++) {
      f16x8 bb0 = *(const f16x8*)(Usm + ((24+u)*2+0)*512 + lane*8);
      f16x8 bb1 = *(const f16x8*)(Usm + ((24+u)*2+1)*512 + lane*8);
      acc0 = __builtin_amdgcn_mfma_f32_16x16x32_f16(a3[u], bb0, acc0, 0, 0, 0);
      acc1 = __builtin_amdgcn_mfma_f32_16x16x32_f16(a3[u], bb1, acc1, 0, 0, 0);
    }
    WAIT_VM(0);
    f16* Hn = Hall + (size_t)(t+1)*B_*H_;
    #pragma unroll
    for (int e = 0; e < 2; e++) {
      int src = quad*16 + cc;
      float f_lo = __shfl(acc0[e],   src);
      float f_hi = __shfl(acc0[2+e], src);
      float i_lo = __shfl(acc0[e],   src + 8);
      float i_hi = __shfl(acc0[2+e], src + 8);
      float o_lo = __shfl(acc1[e],   src);
      float o_hi = __shfl(acc1[2+e], src);
      float a_lo = __shfl(acc1[e],   src + 8);
      float a_hi = __shfl(acc1[2+e], src + 8);
      float pf = (hi ? f_hi : f_lo) + bf0;
      float pi = (hi ? i_hi : i_lo) + bf1;
      float po = (hi ? o_hi : o_lo) + bf2;
      float pa = (hi ? a_hi : a_lo) + bf3;
      float vf = sigm(pf), vi = sigm(pi), vo = sigm(po);
      creg[e] = vi * tanh_(pa) + vf * creg[e];
      float hn = vo * tanh_(creg[e]);
      store_h_sys(Hn + (size_t)(b0r + e)*H_ + colg, (f16)hn);
    }
    if (t + 1 < T_) {
      drain_vmem();             // h stores acked at LLC (nothing before this)
      __syncthreads();
      const int target = t + 1;
      if (tid == 0) store_flag_sys(flags + blk*16, target);
      int pf0 = 0, pf1 = 0;
      const int* fp0 = flags + (2*lane)*16;
      const int* fp1 = flags + (2*lane+1)*16;
      if (w == 0) poll_issue(fp0, fp1, pf0, pf1);
      // all 32 x-projection MFMAs for t+1 in the poll shadow (reg + LDS only)
      xp0 = (f32x4){0.f,0.f,0.f,0.f};
      xp1 = (f32x4){0.f,0.f,0.f,0.f};
      #pragma unroll
      for (int u = 0; u < 8; u++) {
        xp0 = __builtin_amdgcn_mfma_f32_16x16x32_bf16(xa0[u], *(const bf16x8*)((f16*)Wxsm + (u*2+0)*512 + lane*8), xp0, 0, 0, 0);
        xp1 = __builtin_amdgcn_mfma_f32_16x16x32_bf16(xa0[u], *(const bf16x8*)((f16*)Wxsm + (u*2+1)*512 + lane*8), xp1, 0, 0, 0);
      }
      #pragma unroll
      for (int u = 0; u < 8; u++) {
        xp0 = __builtin_amdgcn_mfma_f32_16x16x32_bf16(xa1[u], *(const bf16x8*)((f16*)Wxsm + ((8+u)*2+0)*512 + lane*8), xp0, 0, 0, 0);
        xp1 = __builtin_amdgcn_mfma_f32_16x16x32_bf16(xa1[u], *(const bf16x8*)((f16*)Wxsm + ((8+u)*2+1)*512 + lane*8), xp1, 0, 0, 0);
      }
      __builtin_amdgcn_sched_barrier(0);
      if (w == 0) {
        poll_collect(pf0, pf1);
        while (!__all(pf0 >= target && pf1 >= target))
          load_flag2_sys(fp0, fp1, pf0, pf1);
      }
      __syncthreads();
    } else {
      drain_vmem();             // final h state visible to gemm_out dispatch
    }
  }
}

// out = Hall[1..128] @ Fco^T-layout + ob : M=8192, N=640(pad), K=1024, fp32 out
__global__ __launch_bounds__(256) void gemm_out(
    const f16* __restrict__ A,
    const f16* __restrict__ Bt,
    const float* __restrict__ ob,
    float* __restrict__ out)
{
  const int lane = threadIdx.x & 63, w = threadIdx.x >> 6;
  const int lo = lane & 15, quad = lane >> 4;
  const int m0 = blockIdx.x * 128 + (w >> 1) * 64;
  const int n0 = blockIdx.y * 128 + (w & 1) * 64;
  f32x4 acc[4][4] = {};
  #pragma unroll 2
  for (int k0 = 0; k0 < H_; k0 += 32) {
    f16x8 a[4], b[4];
    #pragma unroll
    for (int mt = 0; mt < 4; mt++)
      a[mt] = *(const f16x8*)(A + (size_t)(m0 + 16*mt + lo) * H_ + k0 + quad*8);
    #pragma unroll
    for (int nt = 0; nt < 4; nt++)
      b[nt] = *(const f16x8*)(Bt + (size_t)(n0 + 16*nt + lo) * H_ + k0 + quad*8);
    #pragma unroll
    for (int mt = 0; mt < 4; mt++)
      #pragma unroll
      for (int nt = 0; nt < 4; nt++)
        acc[mt][nt] = __builtin_amdgcn_mfma_f32_16x16x32_f16(a[mt], b[nt], acc[mt][nt], 0, 0, 0);
  }
  #pragma unroll
  for (int mt = 0; mt < 4; mt++)
    #pragma unroll
    for (int nt = 0; nt < 4; nt++)
      #pragma unroll
      for (int r = 0; r < 4; r++) {
        int row = m0 + 16*mt + quad*4 + r;
        int col = n0 + 16*nt + lo;
        if (col < NO_)
          out[(size_t)row * NO_ + col] = acc[mt][nt][r] + ob[col];
      }
}

extern "C" void kernel_launch(void* const* d_in, const int* in_sizes, int n_in,
                              void* d_out, int out_size, void* d_ws, size_t ws_size,
                              hipStream_t stream)
{
  const void* x   = d_in[0];
  const void* wfw = d_in[1];  const void* wfb = d_in[2];
  const void* wiw = d_in[3];  const void* wib = d_in[4];
  const void* wow = d_in[5];  const void* wob = d_in[6];
  const void* wcw = d_in[7];  const void* wcb = d_in[8];
  const void* ufw = d_in[9];  const void* uiw = d_in[10];
  const void* uow = d_in[11]; const void* ucw = d_in[12];
  const void* fcw = d_in[13]; const void* fcb = d_in[14];

  char* ws = (char*)d_ws;
  unsigned short* Wx = (unsigned short*)(ws + 0);        //  4,194,304 B
  f16*   U    = (f16*)  (ws + 4194304);                  //  8,388,608 B
  f16*   Fco  = (f16*)  (ws + 12582912);                 //  1,310,720 B
  unsigned short* Xc = (unsigned short*)(ws + 13893632); //  8,388,608 B
  f16*   Hall = (f16*)  (ws + 22282240);                 // 16,908,288 B (129 states)
  float* bias = (float*)(ws + 39190528);                 //     16,384 B
  float* ob   = (float*)(ws + 39206912);                 //      2,560 B
  int*   flags= (int*)  (ws + 39209472);                 //      8,192 B (128 x 64B)
  if (ws_size < 39217664u) return;

  pack_kernel<<<PK_TOTAL_BLKS, 256, 0, stream>>>(
      x, wfw, wiw, wow, wcw, wfb, wib, wob, wcb, ufw, uiw, uow, ucw, fcw, fcb,
      Wx, U, Fco, bias, ob, Xc, Hall, flags);

  {
    const unsigned short* Xcp = Xc;
    const unsigned short* Wxp = Wx;
    const f16* Up = U;
    const float* bp = bias;
    f16* Hp = Hall;
    int* flp = flags;
    void* args[] = {&Xcp, &Wxp, &Up, &bp, &Hp, &flp};
    hipLaunchCooperativeKernel((const void*)recur_all, dim3(NBLK_R), dim3(256),
                               args, 0, stream);
  }

  gemm_out<<<dim3(64, 5), 256, 0, stream>>>(Hall + (size_t)B_*H_, Fco, ob, (float*)d_out);
}

// Round 13
// 1132.872 us; speedup vs baseline: 1.0362x; 1.0361x over previous
//
#include <hip/hip_runtime.h>
#include <stdint.h>

typedef _Float16 f16;
typedef _Float16 f16x8 __attribute__((ext_vector_type(8)));
typedef short bf16x8 __attribute__((ext_vector_type(8)));
typedef float f32x4 __attribute__((ext_vector_type(4)));

#define H_ 1024
#define NG_ 4096
#define F_ 512
#define B_ 64
#define T_ 128
#define NOP_ 640
#define NO_ 513
#define NBLK_R 128

// Hamilton block structure: W[p-block(in)][q-block(out)] = sign * comp
__constant__ int c_comp[16] = {0,1,2,3, 1,0,3,2, 2,3,0,1, 3,2,1,0};
__constant__ float c_sgnf[16] = {1,1,1,1, -1,1,1,-1, -1,-1,1,1, -1,1,-1,1};

__device__ __forceinline__ float bf2f(unsigned short u){
  union { unsigned int i; float f; } v; v.i = ((unsigned int)u) << 16; return v.f;
}
__device__ __forceinline__ unsigned short f2bf(float f){
  union { float f; unsigned int i; } v; v.f = f;
  return (unsigned short)((v.i + 0x7fffu + ((v.i >> 16) & 1u)) >> 16);
}
__device__ __forceinline__ float ldin(const void* p, int i, int f){
  return f ? ((const float*)p)[i] : bf2f(((const unsigned short*)p)[i]);
}
__device__ __forceinline__ float sigm(float x){ return 1.f / (1.f + __expf(-x)); }
__device__ __forceinline__ float tanh_(float x){
  float ax = fabsf(x);
  float e = __expf(-2.f * ax);
  float t = (1.f - e) / (1.f + e);
  return x < 0.f ? -t : t;
}

// ---- system-coherent (LLC-level) memory ops: bypass L1/L2 ----
__device__ __forceinline__ void load_a8_nw(const f16* p, f16x8* a){
  asm volatile(
    "global_load_dwordx4 %0, %8, off sc0 sc1\n\t"
    "global_load_dwordx4 %1, %8, off offset:64 sc0 sc1\n\t"
    "global_load_dwordx4 %2, %8, off offset:128 sc0 sc1\n\t"
    "global_load_dwordx4 %3, %8, off offset:192 sc0 sc1\n\t"
    "global_load_dwordx4 %4, %8, off offset:256 sc0 sc1\n\t"
    "global_load_dwordx4 %5, %8, off offset:320 sc0 sc1\n\t"
    "global_load_dwordx4 %6, %8, off offset:384 sc0 sc1\n\t"
    "global_load_dwordx4 %7, %8, off offset:448 sc0 sc1"
    : "=&v"(a[0]),"=&v"(a[1]),"=&v"(a[2]),"=&v"(a[3]),
      "=&v"(a[4]),"=&v"(a[5]),"=&v"(a[6]),"=&v"(a[7])
    : "v"(p) : "memory");
}
// cached (L1/L2) batched loads for the x-prefetch — same 64B-stride pattern
__device__ __forceinline__ void load_c8(const unsigned short* p, bf16x8* a){
  asm volatile(
    "global_load_dwordx4 %0, %8, off\n\t"
    "global_load_dwordx4 %1, %8, off offset:64\n\t"
    "global_load_dwordx4 %2, %8, off offset:128\n\t"
    "global_load_dwordx4 %3, %8, off offset:192\n\t"
    "global_load_dwordx4 %4, %8, off offset:256\n\t"
    "global_load_dwordx4 %5, %8, off offset:320\n\t"
    "global_load_dwordx4 %6, %8, off offset:384\n\t"
    "global_load_dwordx4 %7, %8, off offset:448"
    : "=&v"(a[0]),"=&v"(a[1]),"=&v"(a[2]),"=&v"(a[3]),
      "=&v"(a[4]),"=&v"(a[5]),"=&v"(a[6]),"=&v"(a[7])
    : "v"(p) : "memory");
}
__device__ __forceinline__ void store_h_sys(f16* p, f16 v){
  asm volatile("global_store_short %0, %1, off sc0 sc1" :: "v"(p), "v"(v) : "memory");
}
__device__ __forceinline__ void store_flag_sys(int* p, int v){
  asm volatile("global_store_dword %0, %1, off sc0 sc1" :: "v"(p), "v"(v) : "memory");
}
__device__ __forceinline__ void load_flag2_sys(const int* p0, const int* p1, int &a, int &b){
  asm volatile(
    "global_load_dword %0, %2, off sc0 sc1\n\t"
    "global_load_dword %1, %3, off sc0 sc1\n\t"
    "s_waitcnt vmcnt(0)"
    : "=&v"(a), "=&v"(b) : "v"(p0), "v"(p1) : "memory");
}
__device__ __forceinline__ void drain_vmem(){
  asm volatile("s_waitcnt vmcnt(0)" ::: "memory");
}
#define WAIT_VM(n) do { \
  asm volatile("s_waitcnt vmcnt(" #n ")" ::: "memory"); \
  __builtin_amdgcn_sched_barrier(0); \
} while (0)

// ---- pack: coalesced LDS tile-transposes ----
// sections (blocks): U 1024 | WX 512 | Fco 160 | Xc 1024 | misc 155
#define PK_U_BLKS 1024
#define PK_WX_BLKS 512
#define PK_FCO_BLKS 160
#define PK_XC_BLKS 1024
#define PK_MISC_BLKS 155
#define PK_TOTAL_BLKS (PK_U_BLKS + PK_WX_BLKS + PK_FCO_BLKS + PK_XC_BLKS + PK_MISC_BLKS)

__global__ void pack_kernel(
    const void* __restrict__ x,
    const void* __restrict__ wf, const void* __restrict__ wi,
    const void* __restrict__ wo, const void* __restrict__ wc,
    const void* __restrict__ bfv, const void* __restrict__ biv,
    const void* __restrict__ bov, const void* __restrict__ bcv,
    const void* __restrict__ uf, const void* __restrict__ ui,
    const void* __restrict__ uo, const void* __restrict__ uc,
    const void* __restrict__ fcw, const void* __restrict__ fcb,
    unsigned short* __restrict__ Wx, f16* __restrict__ U, f16* __restrict__ Fco,
    float* __restrict__ bias, float* __restrict__ ob,
    unsigned short* __restrict__ Xc,
    f16* __restrict__ Hz, int* __restrict__ Fz)
{
  __shared__ unsigned short sm[64*68];   // padded 64x64 tile (transpose staging)
  __shared__ int zc, wc2;
  const int tid = threadIdx.x;
  if (tid == 0){ zc = 0; wc2 = 0; }
  __syncthreads();
  {
    const unsigned short* xu = (const unsigned short*)x;
    unsigned short u = xu[2 * tid];
    int e = (u >> 7) & 0xFF;
    bool z = (u & 0x7FFF) == 0;
    bool wild = !z && (e < 67 || e > 150);
    if (z) atomicAdd(&zc, 1);
    if (wild) atomicAdd(&wc2, 1);
  }
  __syncthreads();
  const int fl = (zc >= 128 || wc2 >= 64) ? 1 : 0;

  int b = blockIdx.x;
  if (b < PK_U_BLKS) {
    // U transpose: out U[n*1024+k] = sgn * u_g[comp*65536 + al*256 + be]
    //   n = g*1024 + q*256 + be,  k = p*256 + al
    int g = b >> 8, rem = b & 255;
    int q = rem >> 6, rem2 = rem & 63;
    int p = rem2 >> 4, tt = rem2 & 15;
    int alt = (tt >> 2) * 64, bet = (tt & 3) * 64;
    const void* u = (g==0) ? uf : (g==1) ? ui : (g==2) ? uo : uc;
    int pq = p*4 + q;
    int base_in = c_comp[pq]*65536 + alt*256 + bet;
    float sgn = c_sgnf[pq];
    f16* smf = (f16*)sm;
    #pragma unroll
    for (int j = 0; j < 16; j++) {
      int idx = tid + j*256;
      int al = idx >> 6, be = idx & 63;
      smf[al*68 + be] = (f16)(sgn * ldin(u, base_in + al*256 + be, fl));
    }
    __syncthreads();
    size_t obase = (size_t)(g*1024 + q*256 + bet) * 1024 + p*256 + alt;
    #pragma unroll
    for (int j = 0; j < 16; j++) {
      int idx = tid + j*256;
      int be = idx >> 6, al = idx & 63;
      U[obase + (size_t)be*1024 + al] = smf[al*68 + be];
    }
    return;
  }
  b -= PK_U_BLKS;
  if (b < PK_WX_BLKS) {
    // WX transpose: out Wx[n*512+k] = bf16(sgn * w_g[comp*32768 + al*256 + be])
    //   n = g*1024 + q*256 + be,  k = p*128 + al
    int g = b >> 7, rem = b & 127;
    int q = rem >> 5, rem2 = rem & 31;
    int p = rem2 >> 3, tt = rem2 & 7;
    int alt = (tt >> 2) * 64, bet = (tt & 3) * 64;
    const void* w = (g==0) ? wf : (g==1) ? wi : (g==2) ? wo : wc;
    int pq = p*4 + q;
    int base_in = c_comp[pq]*32768 + alt*256 + bet;
    float sgn = c_sgnf[pq];
    #pragma unroll
    for (int j = 0; j < 16; j++) {
      int idx = tid + j*256;
      int al = idx >> 6, be = idx & 63;
      sm[al*68 + be] = f2bf(sgn * ldin(w, base_in + al*256 + be, fl));
    }
    __syncthreads();
    size_t obase = (size_t)(g*1024 + q*256 + bet) * 512 + p*128 + alt;
    #pragma unroll
    for (int j = 0; j < 16; j++) {
      int idx = tid + j*256;
      int be = idx >> 6, al = idx & 63;
      Wx[obase + (size_t)be*512 + al] = sm[al*68 + be];
    }
    return;
  }
  b -= PK_WX_BLKS;
  if (b < PK_FCO_BLKS) {
    // Fco transpose: out Fco[n*1024+k] = fcw[k*513+n] (n<513 else 0)
    int kt = b / 10, nt2 = b % 10;
    int k0 = kt*64, n0 = nt2*64;
    f16* smf = (f16*)sm;
    #pragma unroll
    for (int j = 0; j < 16; j++) {
      int idx = tid + j*256;
      int kk = idx >> 6, nn = idx & 63;
      int n = n0 + nn;
      smf[kk*68 + nn] = (n < NO_) ? (f16)ldin(fcw, (k0+kk)*NO_ + n, fl) : (f16)0.f;
    }
    __syncthreads();
    #pragma unroll
    for (int j = 0; j < 16; j++) {
      int idx = tid + j*256;
      int nn = idx >> 6, kk = idx & 63;
      Fco[(size_t)(n0+nn)*1024 + k0 + kk] = smf[kk*68 + nn];
    }
    return;
  }
  b -= PK_FCO_BLKS;
  if (b < PK_XC_BLKS) {
    // Xc: 2M uint outputs (4M bf16), vector copy / f32->bf16 pack
    unsigned int* Xo = (unsigned int*)Xc;
    if (fl) {
      const float* xf = (const float*)x;
      #pragma unroll
      for (int j = 0; j < 8; j++) {
        int o = b*2048 + tid + j*256;
        unsigned int lo16 = f2bf(xf[2*o]);
        unsigned int hi16 = f2bf(xf[2*o+1]);
        Xo[o] = lo16 | (hi16 << 16);
      }
    } else {
      const unsigned int* xi = (const unsigned int*)x;
      #pragma unroll
      for (int j = 0; j < 8; j++) {
        int o = b*2048 + tid + j*256;
        Xo[o] = xi[o];
      }
    }
    return;
  }
  b -= PK_XC_BLKS;
  {
    // misc: bias(4096 f32) + ob(640 f32) + Hz(32768 uint) + Fz(2048 int)
    int i = b*256 + tid;
    if (i < 4096) {
      int g = i >> 10;
      const void* bb = (g==0) ? bfv : (g==1) ? biv : (g==2) ? bov : bcv;
      bias[i] = ldin(bb, i & 1023, fl);
      return;
    }
    i -= 4096;
    if (i < 640) { ob[i] = (i < NO_) ? ldin(fcb, i, fl) : 0.f; return; }
    i -= 640;
    if (i < 32768) { ((unsigned int*)Hz)[i] = 0u; return; }
    i -= 32768;
    if (i < 2048) { Fz[i] = 0; }
  }
}

// Persistent cooperative recurrence, ALL 128 steps in one launch.
// 128 blocks x 256 thr (4 waves). Block owns cols jb..jb+8 for ALL 4 gates.
// Per step t:
//   issue h-loads (32 LLC) + x-loads for t+1 (16 cached) together;
//   h-MFMA ladder (x latency hides under it); gate math + h stores;
//   drain -> syncthreads -> tid0 flag post -> 32 x-MFMAs (reg/LDS, poll
//   shadow: the ~250cy of MFMA issue covers flag propagation, so the first
//   poll round usually succeeds) -> wave-0 poll -> syncthreads.
// [session-best configuration: measured 965 us recur / 1138 us total]
__global__ __launch_bounds__(256) void recur_all(
    const unsigned short* __restrict__ Xc,
    const unsigned short* __restrict__ Wxp,
    const f16* __restrict__ U,
    const float* __restrict__ bias,
    f16* __restrict__ Hall,
    int* __restrict__ flags)
{
  __shared__ f16 Usm[32768];             // 64 KB: frag f = ki*2+nt (64), 512 f16
  __shared__ unsigned short Wxsm[16384]; // 32 KB: frag f = u*2+p (32), 512 bf16
  const int blk = blockIdx.x;
  const int jb = blk * 8;
  const int tid = threadIdx.x;
  const int lane = tid & 63, w = tid >> 6;
  const int lo = lane & 15, quad = lane >> 4;
  const int m0 = w * 16;

  #pragma unroll
  for (int j = 0; j < 16; j++) {
    int u = tid + j*256;
    int lp = u & 63, f = u >> 6;
    int ki = f >> 1, nt = f & 1;
    int n = nt*16 + (lp & 15), qd = lp >> 4;
    int row = (n >> 3)*H_ + jb + (n & 7);
    *(f16x8*)(Usm + f*512 + lp*8) =
        *(const f16x8*)(U + (size_t)row*H_ + ki*32 + qd*8);
  }
  #pragma unroll
  for (int j = 0; j < 8; j++) {
    int u = tid + j*256;
    int lp = u & 63, f = u >> 6;      // f = ku*2 + p
    int ku = f >> 1, p = f & 1;
    int col = (p*2 + ((lp & 15) >> 3))*1024 + jb + (lp & 7);
    *(f16x8*)((f16*)Wxsm + f*512 + lp*8) =
        *(const f16x8*)((const f16*)Wxp + (size_t)col*F_ + ku*32 + (lp >> 4)*8);
  }
  const int cc = lane & 7, hi = (lane >> 3) & 1;
  const int colg = jb + cc;
  const int b0r = m0 + quad*4 + hi*2;
  float creg[2] = {0.f, 0.f};
  const float bf0 = bias[colg];
  const float bf1 = bias[1024 + colg];
  const float bf2 = bias[2048 + colg];
  const float bf3 = bias[3072 + colg];
  __syncthreads();

  f32x4 xp0 = {0.f,0.f,0.f,0.f}, xp1 = {0.f,0.f,0.f,0.f};
  bf16x8 xa0[8], xa1[8];
  {
    const unsigned short* xr = Xc + (size_t)(m0 + lo)*F_ + quad*8;
    load_c8(xr, xa0);
    load_c8(xr + 256, xa1);
    drain_vmem();
    __builtin_amdgcn_sched_barrier(0);
    #pragma unroll
    for (int u = 0; u < 8; u++) {
      xp0 = __builtin_amdgcn_mfma_f32_16x16x32_bf16(xa0[u], *(const bf16x8*)((f16*)Wxsm + (u*2+0)*512 + lane*8), xp0, 0, 0, 0);
      xp1 = __builtin_amdgcn_mfma_f32_16x16x32_bf16(xa0[u], *(const bf16x8*)((f16*)Wxsm + (u*2+1)*512 + lane*8), xp1, 0, 0, 0);
    }
    #pragma unroll
    for (int u = 0; u < 8; u++) {
      xp0 = __builtin_amdgcn_mfma_f32_16x16x32_bf16(xa1[u], *(const bf16x8*)((f16*)Wxsm + ((8+u)*2+0)*512 + lane*8), xp0, 0, 0, 0);
      xp1 = __builtin_amdgcn_mfma_f32_16x16x32_bf16(xa1[u], *(const bf16x8*)((f16*)Wxsm + ((8+u)*2+1)*512 + lane*8), xp1, 0, 0, 0);
    }
  }

  for (int t = 0; t < T_; t++) {
    f32x4 acc0 = xp0, acc1 = xp1;
    const f16* Ap = Hall + (size_t)t*B_*H_ + (size_t)(m0 + lo)*H_ + quad*8;
    f16x8 a0[8], a1[8], a2[8], a3[8];
    drain_vmem();
    load_a8_nw(Ap,       a0);
    load_a8_nw(Ap + 256, a1);
    load_a8_nw(Ap + 512, a2);
    load_a8_nw(Ap + 768, a3);
    {
      const int tn = (t + 1 < T_) ? t + 1 : 0;
      const unsigned short* xr = Xc + (size_t)tn*B_*F_ + (size_t)(m0 + lo)*F_ + quad*8;
      load_c8(xr, xa0);
      load_c8(xr + 256, xa1);
    }
    WAIT_VM(40);
    #pragma unroll
    for (int u = 0; u < 8; u++) {
      f16x8 bb0 = *(const f16x8*)(Usm + ((u)*2+0)*512 + lane*8);
      f16x8 bb1 = *(const f16x8*)(Usm + ((u)*2+1)*512 + lane*8);
      acc0 = __builtin_amdgcn_mfma_f32_16x16x32_f16(a0[u], bb0, acc0, 0, 0, 0);
      acc1 = __builtin_amdgcn_mfma_f32_16x16x32_f16(a0[u], bb1, acc1, 0, 0, 0);
    }
    WAIT_VM(32);
    #pragma unroll
    for (int u = 0; u < 8; u++) {
      f16x8 bb0 = *(const f16x8*)(Usm + ((8+u)*2+0)*512 + lane*8);
      f16x8 bb1 = *(const f16x8*)(Usm + ((8+u)*2+1)*512 + lane*8);
      acc0 = __builtin_amdgcn_mfma_f32_16x16x32_f16(a1[u], bb0, acc0, 0, 0, 0);
      acc1 = __builtin_amdgcn_mfma_f32_16x16x32_f16(a1[u], bb1, acc1, 0, 0, 0);
    }
    WAIT_VM(24);
    #pragma unroll
    for (int u = 0; u < 8; u++) {
      f16x8 bb0 = *(const f16x8*)(Usm + ((16+u)*2+0)*512 + lane*8);
      f16x8 bb1 = *(const f16x8*)(Usm + ((16+u)*2+1)*512 + lane*8);
      acc0 = __builtin_amdgcn_mfma_f32_16x16x32_f16(a2[u], bb0, acc0, 0, 0, 0);
      acc1 = __builtin_amdgcn_mfma_f32_16x16x32_f16(a2[u], bb1, acc1, 0, 0, 0);
    }
    WAIT_VM(16);
    #pragma unroll
    for (int u = 0; u < 8; u++) {
      f16x8 bb0 = *(const f16x8*)(Usm + ((24+u)*2+0)*512 + lane*8);
      f16x8 bb1 = *(const f16x8*)(Usm + ((24+u)*2+1)*512 + lane*8);
      acc0 = __builtin_amdgcn_mfma_f32_16x16x32_f16(a3[u], bb0, acc0, 0, 0, 0);
      acc1 = __builtin_amdgcn_mfma_f32_16x16x32_f16(a3[u], bb1, acc1, 0, 0, 0);
    }
    WAIT_VM(0);
    f16* Hn = Hall + (size_t)(t+1)*B_*H_;
    #pragma unroll
    for (int e = 0; e < 2; e++) {
      int src = quad*16 + cc;
      float f_lo = __shfl(acc0[e],   src);
      float f_hi = __shfl(acc0[2+e], src);
      float i_lo = __shfl(acc0[e],   src + 8);
      float i_hi = __shfl(acc0[2+e], src + 8);
      float o_lo = __shfl(acc1[e],   src);
      float o_hi = __shfl(acc1[2+e], src);
      float a_lo = __shfl(acc1[e],   src + 8);
      float a_hi = __shfl(acc1[2+e], src + 8);
      float pf = (hi ? f_hi : f_lo) + bf0;
      float pi = (hi ? i_hi : i_lo) + bf1;
      float po = (hi ? o_hi : o_lo) + bf2;
      float pa = (hi ? a_hi : a_lo) + bf3;
      float vf = sigm(pf), vi = sigm(pi), vo = sigm(po);
      creg[e] = vi * tanh_(pa) + vf * creg[e];
      float hn = vo * tanh_(creg[e]);
      store_h_sys(Hn + (size_t)(b0r + e)*H_ + colg, (f16)hn);
    }
    if (t + 1 < T_) {
      drain_vmem();
      __syncthreads();
      const int target = t + 1;
      if (tid == 0) store_flag_sys(flags + blk*16, target);
      xp0 = (f32x4){0.f,0.f,0.f,0.f};
      xp1 = (f32x4){0.f,0.f,0.f,0.f};
      #pragma unroll
      for (int u = 0; u < 8; u++) {
        xp0 = __builtin_amdgcn_mfma_f32_16x16x32_bf16(xa0[u], *(const bf16x8*)((f16*)Wxsm + (u*2+0)*512 + lane*8), xp0, 0, 0, 0);
        xp1 = __builtin_amdgcn_mfma_f32_16x16x32_bf16(xa0[u], *(const bf16x8*)((f16*)Wxsm + (u*2+1)*512 + lane*8), xp1, 0, 0, 0);
      }
      #pragma unroll
      for (int u = 0; u < 8; u++) {
        xp0 = __builtin_amdgcn_mfma_f32_16x16x32_bf16(xa1[u], *(const bf16x8*)((f16*)Wxsm + ((8+u)*2+0)*512 + lane*8), xp0, 0, 0, 0);
        xp1 = __builtin_amdgcn_mfma_f32_16x16x32_bf16(xa1[u], *(const bf16x8*)((f16*)Wxsm + ((8+u)*2+1)*512 + lane*8), xp1, 0, 0, 0);
      }
      __builtin_amdgcn_sched_barrier(0);
      if (w == 0) {
        const int* fp0 = flags + (2*lane)*16;
        const int* fp1 = flags + (2*lane+1)*16;
        int f0, f1;
        do {
          load_flag2_sys(fp0, fp1, f0, f1);
        } while (!__all(f0 >= target && f1 >= target));
      }
      __syncthreads();
    } else {
      drain_vmem();             // final h state visible to gemm_out dispatch
    }
  }
}

// out = Hall[1..128] @ Fco^T-layout + ob : M=8192, N=640(pad), K=1024, fp32 out
__global__ __launch_bounds__(256) void gemm_out(
    const f16* __restrict__ A,
    const f16* __restrict__ Bt,
    const float* __restrict__ ob,
    float* __restrict__ out)
{
  const int lane = threadIdx.x & 63, w = threadIdx.x >> 6;
  const int lo = lane & 15, quad = lane >> 4;
  const int m0 = blockIdx.x * 128 + (w >> 1) * 64;
  const int n0 = blockIdx.y * 128 + (w & 1) * 64;
  f32x4 acc[4][4] = {};
  #pragma unroll 2
  for (int k0 = 0; k0 < H_; k0 += 32) {
    f16x8 a[4], b[4];
    #pragma unroll
    for (int mt = 0; mt < 4; mt++)
      a[mt] = *(const f16x8*)(A + (size_t)(m0 + 16*mt + lo) * H_ + k0 + quad*8);
    #pragma unroll
    for (int nt = 0; nt < 4; nt++)
      b[nt] = *(const f16x8*)(Bt + (size_t)(n0 + 16*nt + lo) * H_ + k0 + quad*8);
    #pragma unroll
    for (int mt = 0; mt < 4; mt++)
      #pragma unroll
      for (int nt = 0; nt < 4; nt++)
        acc[mt][nt] = __builtin_amdgcn_mfma_f32_16x16x32_f16(a[mt], b[nt], acc[mt][nt], 0, 0, 0);
  }
  #pragma unroll
  for (int mt = 0; mt < 4; mt++)
    #pragma unroll
    for (int nt = 0; nt < 4; nt++)
      #pragma unroll
      for (int r = 0; r < 4; r++) {
        int row = m0 + 16*mt + quad*4 + r;
        int col = n0 + 16*nt + lo;
        if (col < NO_)
          out[(size_t)row * NO_ + col] = acc[mt][nt][r] + ob[col];
      }
}

extern "C" void kernel_launch(void* const* d_in, const int* in_sizes, int n_in,
                              void* d_out, int out_size, void* d_ws, size_t ws_size,
                              hipStream_t stream)
{
  const void* x   = d_in[0];
  const void* wfw = d_in[1];  const void* wfb = d_in[2];
  const void* wiw = d_in[3];  const void* wib = d_in[4];
  const void* wow = d_in[5];  const void* wob = d_in[6];
  const void* wcw = d_in[7];  const void* wcb = d_in[8];
  const void* ufw = d_in[9];  const void* uiw = d_in[10];
  const void* uow = d_in[11]; const void* ucw = d_in[12];
  const void* fcw = d_in[13]; const void* fcb = d_in[14];

  char* ws = (char*)d_ws;
  unsigned short* Wx = (unsigned short*)(ws + 0);        //  4,194,304 B
  f16*   U    = (f16*)  (ws + 4194304);                  //  8,388,608 B
  f16*   Fco  = (f16*)  (ws + 12582912);                 //  1,310,720 B
  unsigned short* Xc = (unsigned short*)(ws + 13893632); //  8,388,608 B
  f16*   Hall = (f16*)  (ws + 22282240);                 // 16,908,288 B (129 states)
  float* bias = (float*)(ws + 39190528);                 //     16,384 B
  float* ob   = (float*)(ws + 39206912);                 //      2,560 B
  int*   flags= (int*)  (ws + 39209472);                 //      8,192 B (128 x 64B)
  if (ws_size < 39217664u) return;

  pack_kernel<<<PK_TOTAL_BLKS, 256, 0, stream>>>(
      x, wfw, wiw, wow, wcw, wfb, wib, wob, wcb, ufw, uiw, uow, ucw, fcw, fcb,
      Wx, U, Fco, bias, ob, Xc, Hall, flags);

  {
    const unsigned short* Xcp = Xc;
    const unsigned short* Wxp = Wx;
    const f16* Up = U;
    const float* bp = bias;
    f16* Hp = Hall;
    int* flp = flags;
    void* args[] = {&Xcp, &Wxp, &Up, &bp, &Hp, &flp};
    hipLaunchCooperativeKernel((const void*)recur_all, dim3(NBLK_R), dim3(256),
                               args, 0, stream);
  }

  gemm_out<<<dim3(64, 5), 256, 0, stream>>>(Hall + (size_t)B_*H_, Fco, ob, (float*)d_out);
}